// Round 5
// baseline (352.788 us; speedup 1.0000x reference)
//
#include <hip/hip_runtime.h>

#define CRANGE 3.75f       // 15.0 / 4 layers

typedef _Float16 half_t;
typedef __attribute__((ext_vector_type(8))) _Float16 half8;
typedef __attribute__((ext_vector_type(4))) _Float16 half4;
typedef __attribute__((ext_vector_type(4))) float f32x4;

__device__ __forceinline__ float frcp(float x) { return __builtin_amdgcn_rcpf(x); }
__device__ __forceinline__ float fexpn(float x) { return __expf(fminf(x, 20.f)); } // clamp: 4-product of (1+e^20) stays < f32 max
__device__ __forceinline__ float fsilu(float x) { return x * frcp(1.f + fexpn(-x)); }

// batch 4 reciprocals of d0..d3 through ONE v_rcp
__device__ __forceinline__ void inv4(float d0, float d1, float d2, float d3, float* o) {
    float p01 = d0 * d1, p23 = d2 * d3;
    float r = frcp(p01 * p23);
    float t01 = p23 * r, t23 = p01 * r;
    o[0] = d1 * t01; o[1] = d0 * t01; o[2] = d3 * t23; o[3] = d2 * t23;
}
__device__ __forceinline__ void silu4(const float* x, float* o) {
    float d0 = 1.f + fexpn(-x[0]), d1 = 1.f + fexpn(-x[1]);
    float d2 = 1.f + fexpn(-x[2]), d3 = 1.f + fexpn(-x[3]);
    float iv[4]; inv4(d0, d1, d2, d3, iv);
    o[0] = x[0] * iv[0]; o[1] = x[1] * iv[1]; o[2] = x[2] * iv[2]; o[3] = x[3] * iv[3];
}

// ---------------- K_prep: f16 A-frags for W2/Wc1 + transposed node/edge1 weights ----------------
__global__ void k_prep(const float* __restrict__ ew2, const float* __restrict__ cw1,
                       const float* __restrict__ nw1, const float* __restrict__ nw2,
                       const float* __restrict__ ew1,
                       half_t* __restrict__ wf, float* __restrict__ trT) {
    int idx = blockIdx.x * 256 + threadIdx.x;
    if (idx < 4096) {
        int lane = idx & 63;
        int g = (idx >> 6) & 7;
        int mat = (idx >> 9) & 1;
        int l = idx >> 10;
        int mt = g >> 1, kc = g & 1;
        int c = lane & 15, qq = lane >> 4;
        const float* W = (mat ? cw1 : ew2) + l * 4096;
        int row = 16 * mt + c;
        int k0 = 32 * kc + 8 * qq;
        half8 pk;
#pragma unroll
        for (int j = 0; j < 8; ++j) pk[j] = (half_t)W[row * 64 + k0 + j];
        ((half8*)wf)[idx] = pk;
    }
    int tid2 = idx - 4096;
    if (tid2 >= 0 && tid2 < 81920) {
        int l = tid2 / 20480, r = tid2 % 20480;
        float v;
        if (r < 8192)       { int k = r >> 6,        c = r & 63; v = nw1[l * 8192 + c * 128 + k]; }
        else if (r < 12288) { int r2 = r - 8192,  k = r2 >> 6, c = r2 & 63; v = nw2[l * 4096 + c * 64 + k]; }
        else if (r < 16384) { int r2 = r - 12288, k = r2 >> 6, c = r2 & 63; v = ew1[l * 8320 + c * 130 + k]; }
        else                { int r2 = r - 16384, k = r2 >> 6, c = r2 & 63; v = ew1[l * 8320 + c * 130 + 64 + k]; }
        trT[l * 20480 + r] = v;
    }
}

// ---------------- K_init: embedding + x0 + layer-0 Hr/Hc (one node per block) ----------------
__global__ void k_init(const float* __restrict__ t, const float* __restrict__ x,
                       const float* __restrict__ at, const float* __restrict__ aa,
                       const float* __restrict__ ap, const float* __restrict__ nm,
                       const float* __restrict__ embw, const float* __restrict__ embb,
                       const float* __restrict__ ew1aT0, const float* __restrict__ ew1bT0,
                       const float* __restrict__ eb1_0,
                       float* __restrict__ h, float* __restrict__ Hr, float* __restrict__ HcA,
                       float* __restrict__ x0, float* __restrict__ cA) {
    int n = blockIdx.x, c = threadIdx.x;
    __shared__ float sh[64];
    float m = nm[n]; int b = n >> 8;
    float i0 = at[n] * m, i1 = aa[n] * m, i2 = ap[n] * m, i3 = t[b] * m;
    float4 w = ((const float4*)embw)[c];
    float hv = w.x * i0 + w.y * i1 + w.z * i2 + w.w * i3 + embb[c];
    sh[c] = hv; h[n * 64 + c] = hv;
    if (c < 3) { float v = x[n * 3 + c] * m; x0[n * 3 + c] = v; cA[n * 3 + c] = v; }
    __syncthreads();
    float a = eb1_0[c], bb = 0.f;
#pragma unroll
    for (int k = 0; k < 64; ++k) {
        float hk = sh[k];
        a  += ew1aT0[k * 64 + c] * hk;
        bb += ew1bT0[k * 64 + c] * hk;
    }
    Hr[n * 64 + c] = a;
    HcA[n * 64 + c] = bb;
}

// ---------------- K2: fused edge + node MLP + next-layer pre (one block per dest node) ----------------
// LDS cut to ~22.5KB by k-chunking the frag buffer (4KB/wave holds one 32-k chunk;
// both GEMMs accumulate over chunks in registers; same-wave DS ops are in-order so
// chunk overwrite is WAR-safe without barriers). R4: 39.4KB LDS -> 2.2 blocks/CU,
// VALU idle 45%. Target: 5-7 blocks/CU.
__global__ __launch_bounds__(256, 3) void k_edge(
    const float* __restrict__ coordIn, const float* __restrict__ x0,
    float* __restrict__ Hr, const float* __restrict__ Hc,
    const float* __restrict__ ew1, const float* __restrict__ eb2,
    const float* __restrict__ cb1, const float* __restrict__ attw,
    const float* __restrict__ attb, const float* __restrict__ cw2,
    const float* __restrict__ nm, const half_t* __restrict__ wf2,
    const half_t* __restrict__ wf1,
    float* __restrict__ hbuf,
    const float* __restrict__ nw1T, const float* __restrict__ nw2T,
    const float* __restrict__ nb1, const float* __restrict__ nb2,
    const float* __restrict__ ew1aTn, const float* __restrict__ ew1bTn,
    const float* __restrict__ eb1n,
    float* __restrict__ HcO, float* __restrict__ coordOut)
{
    __shared__ __align__(16) half_t sV[4][2048];   // per-wave: 4 B-frags = one 32-k chunk; tail aliases
    __shared__ __align__(16) float sGeo[4][64][4]; // ndx ndy ndz em
    __shared__ float sHr[64], sWr[64], sWe[64], sB2[64], sBc1[64], sAttw[64], sWc2[64];
    __shared__ float sAgg[64];
    __shared__ float sCoord[3];

    const int i = blockIdx.x, b = i >> 8, ir = i & 255;
    const int t = threadIdx.x, wv = t >> 6, e = t & 63;
    const int q = e >> 4, c = e & 15;
    const int col = (b << 8) + t;

    if (t < 64) {
        sHr[t] = Hr[i * 64 + t];
        sWr[t] = ew1[t * 130 + 128];
        sWe[t] = ew1[t * 130 + 129];
        sB2[t] = eb2[t]; sBc1[t] = cb1[t]; sAttw[t] = attw[t]; sWc2[t] = cw2[t];
        sAgg[t] = 0.f;
    }
    if (t == 64) { sCoord[0] = 0.f; sCoord[1] = 0.f; sCoord[2] = 0.f; }
    float attb0 = attb[0];
    float nmi = nm[i];

    // ---- geometry ----
    float dx = coordIn[i*3+0] - coordIn[col*3+0];
    float dy = coordIn[i*3+1] - coordIn[col*3+1];
    float dz = coordIn[i*3+2] - coordIn[col*3+2];
    float radial = dx*dx + dy*dy + dz*dz;
    float inv = frcp(__builtin_amdgcn_sqrtf(radial + 1e-8f) + 1.f);
    float ex = x0[i*3+0] - x0[col*3+0];
    float ey = x0[i*3+1] - x0[col*3+1];
    float ez = x0[i*3+2] - x0[col*3+2];
    float e0 = ex*ex + ey*ey + ez*ez;
    float em = nmi * nm[col] * ((t == ir) ? 0.f : 1.f);

    __syncthreads();

    {
        float4 g4 = make_float4(dx*inv, dy*inv, dz*inv, em);
        *(float4*)&sGeo[wv][e][0] = g4;
    }

    half_t* mybuf = (half_t*)sV[wv];
    const half8* bv = (const half8*)mybuf;
    const float4* hcv = (const float4*)(Hc + col * 64);

    // A-frags for both GEMMs (a2 now, a1 prefetched after GEMM1)
    half8 a2[8];
    {
        const half8* a2v = (const half8*)wf2;
#pragma unroll
        for (int g = 0; g < 8; ++g) a2[g] = a2v[g * 64 + e];
    }

    // ---- v0 = silu(Hr[i] + Hc[col] + radial*wr + e0*we) + GEMM1, k-chunked ----
    f32x4 acc[4][4];
#pragma unroll
    for (int mt = 0; mt < 4; ++mt)
#pragma unroll
        for (int nt = 0; nt < 4; ++nt)
#pragma unroll
            for (int r = 0; r < 4; ++r) acc[mt][nt][r] = 0.f;

#pragma unroll
    for (int kc = 0; kc < 2; ++kc) {
#pragma unroll
        for (int s2 = 0; s2 < 4; ++s2) {
            int s = kc * 4 + s2;
            float4 ha = hcv[2*s], hb = hcv[2*s+1];
            float z[8], so[8];
            z[0]=ha.x; z[1]=ha.y; z[2]=ha.z; z[3]=ha.w;
            z[4]=hb.x; z[5]=hb.y; z[6]=hb.z; z[7]=hb.w;
#pragma unroll
            for (int u = 0; u < 8; ++u) {
                int k = 8*s + u;
                z[u] = sHr[k] + z[u] + radial * sWr[k] + e0 * sWe[k];
            }
            silu4(z, so); silu4(z + 4, so + 4);
            half8 pk;
#pragma unroll
            for (int u = 0; u < 8; ++u) pk[u] = (half_t)so[u];
            *(half8*)&mybuf[q * 512 + (s2 * 16 + c) * 8] = pk;
        }
#pragma unroll
        for (int nt = 0; nt < 4; ++nt) {
            half8 b0 = bv[nt * 64 + e];
#pragma unroll
            for (int mt = 0; mt < 4; ++mt)
                acc[mt][nt] = __builtin_amdgcn_mfma_f32_16x16x32_f16(a2[mt*2+kc], b0, acc[mt][nt], 0, 0, 0);
        }
    }

    half8 a1[8];
    {
        const half8* a1v = (const half8*)wf1;
#pragma unroll
        for (int g = 0; g < 8; ++g) a1[g] = a1v[g * 64 + e];
    }

    // ---- bias + silu + attention dot (full register tile) ----
    float attp[4] = {0.f, 0.f, 0.f, 0.f};
#pragma unroll
    for (int mt = 0; mt < 4; ++mt) {
        int row0 = 16*mt + 4*q;
#pragma unroll
        for (int nt = 0; nt < 4; ++nt) {
            float z[4], so[4];
#pragma unroll
            for (int r = 0; r < 4; ++r) z[r] = acc[mt][nt][r] + sB2[row0 + r];
            silu4(z, so);
#pragma unroll
            for (int r = 0; r < 4; ++r) {
                acc[mt][nt][r] = so[r];
                attp[nt] += so[r] * sAttw[row0 + r];
            }
        }
    }
#pragma unroll
    for (int nt = 0; nt < 4; ++nt) {
        float v = attp[nt];
        v += __shfl_xor(v, 16);
        v += __shfl_xor(v, 32);
        attp[nt] = v;
    }
    float scale[4];
    {
        float d0 = 1.f + fexpn(-(attp[0] + attb0));
        float d1 = 1.f + fexpn(-(attp[1] + attb0));
        float d2 = 1.f + fexpn(-(attp[2] + attb0));
        float d3 = 1.f + fexpn(-(attp[3] + attb0));
        float iv[4]; inv4(d0, d1, d2, d3, iv);
#pragma unroll
        for (int nt = 0; nt < 4; ++nt) scale[nt] = iv[nt] * sGeo[wv][16*nt + c][3];
    }

    // ---- gate + agg partials + GEMM2, k-chunked (rows 0..31 then 32..63) ----
    float aggp[4][4];
#pragma unroll
    for (int mt = 0; mt < 4; ++mt)
#pragma unroll
        for (int r = 0; r < 4; ++r) aggp[mt][r] = 0.f;

    f32x4 acc2[4][4];
#pragma unroll
    for (int mt = 0; mt < 4; ++mt)
#pragma unroll
        for (int nt = 0; nt < 4; ++nt)
#pragma unroll
            for (int r = 0; r < 4; ++r) acc2[mt][nt][r] = 0.f;

#pragma unroll
    for (int kc = 0; kc < 2; ++kc) {
#pragma unroll
        for (int mi = 0; mi < 2; ++mi) {
            int mt = kc * 2 + mi;
            int kbase = 16*mt + 4*q;
            int off = (((kbase >> 3) & 3) * 128) + (kbase & 7) + c * 8;
#pragma unroll
            for (int nt = 0; nt < 4; ++nt) {
                half4 pk;
#pragma unroll
                for (int r = 0; r < 4; ++r) {
                    float v = acc[mt][nt][r] * scale[nt];
                    aggp[mt][r] += v;
                    pk[r] = (half_t)v;
                }
                *(half4*)&mybuf[nt * 512 + off] = pk;
            }
        }
#pragma unroll
        for (int nt = 0; nt < 4; ++nt) {
            half8 b0 = bv[nt * 64 + e];
#pragma unroll
            for (int mt = 0; mt < 4; ++mt)
                acc2[mt][nt] = __builtin_amdgcn_mfma_f32_16x16x32_f16(a1[mt*2+kc], b0, acc2[mt][nt], 0, 0, 0);
        }
    }

#pragma unroll
    for (int mt = 0; mt < 4; ++mt)
#pragma unroll
        for (int r = 0; r < 4; ++r) {
            float v = aggp[mt][r];
            v += __shfl_xor(v, 1); v += __shfl_xor(v, 2);
            v += __shfl_xor(v, 4); v += __shfl_xor(v, 8);
            if (c == 0) atomicAdd(&sAgg[16*mt + 4*q + r], v);
        }

    // ---- phi = tanh( silu(D2 + bc1) . wc2 ), trans, coord reduction ----
    float php[4] = {0.f, 0.f, 0.f, 0.f};
#pragma unroll
    for (int mt = 0; mt < 4; ++mt) {
        int row0 = 16*mt + 4*q;
#pragma unroll
        for (int nt = 0; nt < 4; ++nt) {
            float z[4], so[4];
#pragma unroll
            for (int r = 0; r < 4; ++r) z[r] = acc2[mt][nt][r] + sBc1[row0 + r];
            silu4(z, so);
#pragma unroll
            for (int r = 0; r < 4; ++r) php[nt] += so[r] * sWc2[row0 + r];
        }
    }
#pragma unroll
    for (int nt = 0; nt < 4; ++nt) {
        float v = php[nt];
        v += __shfl_xor(v, 16);
        v += __shfl_xor(v, 32);
        php[nt] = v;
    }
    float tnh[4];
    {
        float d0 = fexpn(2.f * php[0]) + 1.f;
        float d1 = fexpn(2.f * php[1]) + 1.f;
        float d2 = fexpn(2.f * php[2]) + 1.f;
        float d3 = fexpn(2.f * php[3]) + 1.f;
        float iv[4]; inv4(d0, d1, d2, d3, iv);
#pragma unroll
        for (int nt = 0; nt < 4; ++nt) tnh[nt] = 1.f - 2.f * iv[nt];
    }
    float tx = 0.f, ty = 0.f, tz = 0.f;
#pragma unroll
    for (int nt = 0; nt < 4; ++nt) {
        float4 g4 = *(float4*)&sGeo[wv][16*nt + c][0];
        float tr = tnh[nt] * CRANGE * g4.w;
        tx += g4.x * tr; ty += g4.y * tr; tz += g4.z * tr;
    }
    tx += __shfl_xor(tx, 1); tx += __shfl_xor(tx, 2); tx += __shfl_xor(tx, 4); tx += __shfl_xor(tx, 8);
    ty += __shfl_xor(ty, 1); ty += __shfl_xor(ty, 2); ty += __shfl_xor(ty, 4); ty += __shfl_xor(ty, 8);
    tz += __shfl_xor(tz, 1); tz += __shfl_xor(tz, 2); tz += __shfl_xor(tz, 4); tz += __shfl_xor(tz, 8);
    if (e == 0) {
        atomicAdd(&sCoord[0], tx);
        atomicAdd(&sCoord[1], ty);
        atomicAdd(&sCoord[2], tz);
    }

    __syncthreads();   // sAgg / sCoord complete; sV free for reuse

    // ================= fused tail: node MLP + next-layer Hr/Hc =================
    float* sT   = (float*)&sV[0][0];
    float* sIn  = sT;           // 128
    float* sP   = sT + 128;     // 256
    float* sU   = sT + 384;     // 64
    float* sHn  = sT + 448;     // 64
    float* sPB  = sT + 512;     // 256

    if (t < 64) sIn[t] = hbuf[i * 64 + t];
    else if (t < 128) sIn[t] = sAgg[t - 64];
    if (t >= 128 && t < 131) {
        int d = t - 128;
        coordOut[i * 3 + d] = (coordIn[i * 3 + d] + sCoord[d]) * nmi;
    }
    __syncthreads();

    const int cc = t & 63, p = t >> 6;
    {
        float a = 0.f;
        const float* w = nw1T + (p * 32) * 64 + cc;
#pragma unroll
        for (int k = 0; k < 32; ++k) a += w[k * 64] * sIn[p * 32 + k];
        sP[p * 64 + cc] = a;
    }
    __syncthreads();
    if (t < 64) sU[t] = fsilu(sP[t] + sP[64 + t] + sP[128 + t] + sP[192 + t] + nb1[t]);
    __syncthreads();
    {
        float a = 0.f;
        const float* w = nw2T + (p * 16) * 64 + cc;
#pragma unroll
        for (int k = 0; k < 16; ++k) a += w[k * 64] * sU[p * 16 + k];
        sP[p * 64 + cc] = a;
    }
    __syncthreads();
    if (t < 64) {
        float hn = (sIn[t] + sP[t] + sP[64 + t] + sP[128 + t] + sP[192 + t] + nb2[t]) * nmi;
        hbuf[i * 64 + t] = hn;
        sHn[t] = hn;
    }
    __syncthreads();
    {
        float a = 0.f, b2 = 0.f;
        const float* wa = ew1aTn + (p * 16) * 64 + cc;
        const float* wb = ew1bTn + (p * 16) * 64 + cc;
#pragma unroll
        for (int k = 0; k < 16; ++k) {
            float hv = sHn[p * 16 + k];
            a  += wa[k * 64] * hv;
            b2 += wb[k * 64] * hv;
        }
        sP[p * 64 + cc] = a;
        sPB[p * 64 + cc] = b2;
    }
    __syncthreads();
    if (t < 64) {
        Hr[i * 64 + t]  = sP[t] + sP[64 + t] + sP[128 + t] + sP[192 + t] + eb1n[t];
        HcO[i * 64 + t] = sPB[t] + sPB[64 + t] + sPB[128 + t] + sPB[192 + t];
    }
}

// ---------------- K4: vel = coord - x0, remove masked mean per batch ----------------
__global__ void k_final(const float* __restrict__ coord, const float* __restrict__ x0,
                        const float* __restrict__ nm, float* __restrict__ out) {
    int b = blockIdx.x;
    int t = threadIdx.x;
    int i = b * 256 + t;
    int lane = t & 63;
    float m = nm[i];
    float vx = (coord[i * 3 + 0] - x0[i * 3 + 0]) * m;
    float vy = (coord[i * 3 + 1] - x0[i * 3 + 1]) * m;
    float vz = (coord[i * 3 + 2] - x0[i * 3 + 2]) * m;
    __shared__ float red[4];
    if (t < 4) red[t] = 0.f;
    __syncthreads();
    float sx = vx, sy = vy, sz = vz, sn = m;
#pragma unroll
    for (int off = 1; off < 64; off <<= 1) {
        sx += __shfl_xor(sx, off);
        sy += __shfl_xor(sy, off);
        sz += __shfl_xor(sz, off);
        sn += __shfl_xor(sn, off);
    }
    if (lane == 0) {
        atomicAdd(&red[0], sx); atomicAdd(&red[1], sy);
        atomicAdd(&red[2], sz); atomicAdd(&red[3], sn);
    }
    __syncthreads();
    float invNs = frcp(red[3]);
    out[b * 768 + t * 3 + 0] = vx - red[0] * invNs * m;
    out[b * 768 + t * 3 + 1] = vy - red[1] * invNs * m;
    out[b * 768 + t * 3 + 2] = vz - red[2] * invNs * m;
}

extern "C" void kernel_launch(void* const* d_in, const int* in_sizes, int n_in,
                              void* d_out, int out_size, void* d_ws, size_t ws_size,
                              hipStream_t stream) {
    const float* t_in    = (const float*)d_in[0];
    const float* x_in    = (const float*)d_in[1];
    const float* at_in   = (const float*)d_in[2];
    const float* aa_in   = (const float*)d_in[3];
    const float* ap_in   = (const float*)d_in[4];
    const float* nm_in   = (const float*)d_in[5];
    const float* emb_w   = (const float*)d_in[6];
    const float* emb_b   = (const float*)d_in[7];
    const float* edge_w1 = (const float*)d_in[8];
    const float* edge_b1 = (const float*)d_in[9];
    const float* edge_w2 = (const float*)d_in[10];
    const float* edge_b2 = (const float*)d_in[11];
    const float* node_w1 = (const float*)d_in[12];
    const float* node_b1 = (const float*)d_in[13];
    const float* node_w2 = (const float*)d_in[14];
    const float* node_b2 = (const float*)d_in[15];
    const float* coord_w1= (const float*)d_in[16];
    const float* coord_b1= (const float*)d_in[17];
    const float* att_w   = (const float*)d_in[18];
    const float* att_b   = (const float*)d_in[19];
    const float* coord_w2= (const float*)d_in[20];

    float* ws  = (float*)d_ws;
    float* h   = ws;                  // 131072
    float* Hr  = h + 131072;          // 131072
    float* HcA = Hr + 131072;         // 131072
    float* HcB = HcA + 131072;        // 131072
    float* x0  = HcB + 131072;        // 6144
    float* cA  = x0 + 6144;           // 6144
    float* cB  = cA + 6144;           // 6144
    float* base = cB + 6144;
    half_t* wf = (half_t*)base;       // 32768 halves = 16384 float slots
    float* trT = base + 16384;        // 81920 floats: per layer [nw1T 8192][nw2T 4096][ew1aT 4096][ew1bT 4096]

    float* out = (float*)d_out;

    k_prep<<<336, 256, 0, stream>>>(edge_w2, coord_w1, node_w1, node_w2, edge_w1, wf, trT);
    k_init<<<2048, 64, 0, stream>>>(t_in, x_in, at_in, aa_in, ap_in, nm_in, emb_w, emb_b,
                                    trT + 12288, trT + 16384, edge_b1,
                                    h, Hr, HcA, x0, cA);

    for (int l = 0; l < 4; ++l) {
        const float* ew1 = edge_w1 + l * 8320;
        const float* eb2 = edge_b2 + l * 64;
        const float* cb1 = coord_b1 + l * 64;
        const float* aw  = att_w + l * 64;
        const float* ab  = att_b + l;
        const float* cw2 = coord_w2 + l * 64;
        const float* nb1 = node_b1 + l * 64;
        const float* nb2 = node_b2 + l * 64;

        const float* trL = trT + l * 20480;
        int ln = (l + 1) & 3;
        const float* trN = trT + ln * 20480;

        const float* cin  = (l & 1) ? cB : cA;
        float*       cout = (l & 1) ? cA : cB;
        const float* HcR  = (l & 1) ? HcB : HcA;
        float*       HcW  = (l & 1) ? HcA : HcB;

        k_edge<<<2048, 256, 0, stream>>>(cin, x0, Hr, HcR, ew1, eb2, cb1,
                                         aw, ab, cw2, nm_in,
                                         wf + l * 8192, wf + l * 8192 + 4096,
                                         h, trL, trL + 8192, nb1, nb2,
                                         trN + 12288, trN + 16384, edge_b1 + ln * 64,
                                         HcW, cout);
    }

    k_final<<<8, 256, 0, stream>>>(cA, x0, nm_in, out);
}

// Round 6
// 304.104 us; speedup vs baseline: 1.1601x; 1.1601x over previous
//
#include <hip/hip_runtime.h>

#define CRANGE 3.75f       // 15.0 / 4 layers

typedef _Float16 half_t;
typedef __attribute__((ext_vector_type(8))) _Float16 half8;
typedef __attribute__((ext_vector_type(4))) _Float16 half4;
typedef __attribute__((ext_vector_type(4))) float f32x4;

__device__ __forceinline__ float frcp(float x) { return __builtin_amdgcn_rcpf(x); }
__device__ __forceinline__ float fexpn(float x) { return __expf(fminf(x, 20.f)); } // clamp: 4-product of (1+e^20) stays < f32 max
__device__ __forceinline__ float fsilu(float x) { return x * frcp(1.f + fexpn(-x)); }

// batch 4 reciprocals of d0..d3 through ONE v_rcp
__device__ __forceinline__ void inv4(float d0, float d1, float d2, float d3, float* o) {
    float p01 = d0 * d1, p23 = d2 * d3;
    float r = frcp(p01 * p23);
    float t01 = p23 * r, t23 = p01 * r;
    o[0] = d1 * t01; o[1] = d0 * t01; o[2] = d3 * t23; o[3] = d2 * t23;
}
__device__ __forceinline__ void silu4(const float* x, float* o) {
    float d0 = 1.f + fexpn(-x[0]), d1 = 1.f + fexpn(-x[1]);
    float d2 = 1.f + fexpn(-x[2]), d3 = 1.f + fexpn(-x[3]);
    float iv[4]; inv4(d0, d1, d2, d3, iv);
    o[0] = x[0] * iv[0]; o[1] = x[1] * iv[1]; o[2] = x[2] * iv[2]; o[3] = x[3] * iv[3];
}

// ---------------- K_prep: f16 A-frags for W2/Wc1 + transposed node/edge1 weights ----------------
__global__ void k_prep(const float* __restrict__ ew2, const float* __restrict__ cw1,
                       const float* __restrict__ nw1, const float* __restrict__ nw2,
                       const float* __restrict__ ew1,
                       half_t* __restrict__ wf, float* __restrict__ trT) {
    int idx = blockIdx.x * 256 + threadIdx.x;
    if (idx < 4096) {
        int lane = idx & 63;
        int g = (idx >> 6) & 7;
        int mat = (idx >> 9) & 1;
        int l = idx >> 10;
        int mt = g >> 1, kc = g & 1;
        int c = lane & 15, qq = lane >> 4;
        const float* W = (mat ? cw1 : ew2) + l * 4096;
        int row = 16 * mt + c;
        int k0 = 32 * kc + 8 * qq;
        half8 pk;
#pragma unroll
        for (int j = 0; j < 8; ++j) pk[j] = (half_t)W[row * 64 + k0 + j];
        ((half8*)wf)[idx] = pk;
    }
    int tid2 = idx - 4096;
    if (tid2 >= 0 && tid2 < 81920) {
        int l = tid2 / 20480, r = tid2 % 20480;
        float v;
        if (r < 8192)       { int k = r >> 6,        c = r & 63; v = nw1[l * 8192 + c * 128 + k]; }
        else if (r < 12288) { int r2 = r - 8192,  k = r2 >> 6, c = r2 & 63; v = nw2[l * 4096 + c * 64 + k]; }
        else if (r < 16384) { int r2 = r - 12288, k = r2 >> 6, c = r2 & 63; v = ew1[l * 8320 + c * 130 + k]; }
        else                { int r2 = r - 16384, k = r2 >> 6, c = r2 & 63; v = ew1[l * 8320 + c * 130 + 64 + k]; }
        trT[l * 20480 + r] = v;
    }
}

// ---------------- K_init: embedding + x0 + layer-0 Hr/Hc (one node per block) ----------------
__global__ void k_init(const float* __restrict__ t, const float* __restrict__ x,
                       const float* __restrict__ at, const float* __restrict__ aa,
                       const float* __restrict__ ap, const float* __restrict__ nm,
                       const float* __restrict__ embw, const float* __restrict__ embb,
                       const float* __restrict__ ew1aT0, const float* __restrict__ ew1bT0,
                       const float* __restrict__ eb1_0,
                       float* __restrict__ h, float* __restrict__ Hr, float* __restrict__ HcA,
                       float* __restrict__ x0, float* __restrict__ cA) {
    int n = blockIdx.x, c = threadIdx.x;
    __shared__ float sh[64];
    float m = nm[n]; int b = n >> 8;
    float i0 = at[n] * m, i1 = aa[n] * m, i2 = ap[n] * m, i3 = t[b] * m;
    float4 w = ((const float4*)embw)[c];
    float hv = w.x * i0 + w.y * i1 + w.z * i2 + w.w * i3 + embb[c];
    sh[c] = hv; h[n * 64 + c] = hv;
    if (c < 3) { float v = x[n * 3 + c] * m; x0[n * 3 + c] = v; cA[n * 3 + c] = v; }
    __syncthreads();
    float a = eb1_0[c], bb = 0.f;
#pragma unroll
    for (int k = 0; k < 64; ++k) {
        float hk = sh[k];
        a  += ew1aT0[k * 64 + c] * hk;
        bb += ew1bT0[k * 64 + c] * hk;
    }
    Hr[n * 64 + c] = a;
    HcA[n * 64 + c] = bb;
}

// ---------------- K2: fused edge + node MLP + next-layer pre (one block per dest node) ----------------
// Register discipline (R5 post-mortem: occupancy is REGISTER-bound, VGPR+AGPR unified):
//  - R4 sequencing: acc fully consumed in gate before acc2 exists (never both live)
//  - a1 loaded only after mg writes (acc dead) -> a1 never coexists with acc
//  - bias as MFMA C-init (replaces zero-init for free, kills 128 adds/lane)
//  Peak combined ~110 < 128 -> 4 waves/SIMD. LDS 39424*4 = 157.7KB fits 4 blocks/CU.
__global__ __launch_bounds__(256, 4) void k_edge(
    const float* __restrict__ coordIn, const float* __restrict__ x0,
    float* __restrict__ Hr, const float* __restrict__ Hc,
    const float* __restrict__ ew1, const float* __restrict__ eb2,
    const float* __restrict__ cb1, const float* __restrict__ attw,
    const float* __restrict__ attb, const float* __restrict__ cw2,
    const float* __restrict__ nm, const half_t* __restrict__ wf2,
    const half_t* __restrict__ wf1,
    float* __restrict__ hbuf,
    const float* __restrict__ nw1T, const float* __restrict__ nw2T,
    const float* __restrict__ nb1, const float* __restrict__ nb2,
    const float* __restrict__ ew1aTn, const float* __restrict__ ew1bTn,
    const float* __restrict__ eb1n,
    float* __restrict__ HcO, float* __restrict__ coordOut)
{
    __shared__ __align__(16) half_t sV[4][4096];   // per-wave frag buffer (v0 then mg); tail aliases
    __shared__ __align__(16) float sGeo[4][64][4]; // ndx ndy ndz em
    __shared__ float sHr[64], sWr[64], sWe[64], sB2[64], sBc1[64], sAttw[64], sWc2[64];
    __shared__ float sAgg[64];
    __shared__ float sCoord[3];

    const int i = blockIdx.x, b = i >> 8, ir = i & 255;
    const int t = threadIdx.x, wv = t >> 6, e = t & 63;
    const int q = e >> 4, c = e & 15;
    const int col = (b << 8) + t;

    if (t < 64) {
        sHr[t] = Hr[i * 64 + t];
        sWr[t] = ew1[t * 130 + 128];
        sWe[t] = ew1[t * 130 + 129];
        sB2[t] = eb2[t]; sBc1[t] = cb1[t]; sAttw[t] = attw[t]; sWc2[t] = cw2[t];
        sAgg[t] = 0.f;
    }
    if (t == 64) { sCoord[0] = 0.f; sCoord[1] = 0.f; sCoord[2] = 0.f; }
    float attb0 = attb[0];
    float nmi = nm[i];

    // ---- geometry ----
    float dx = coordIn[i*3+0] - coordIn[col*3+0];
    float dy = coordIn[i*3+1] - coordIn[col*3+1];
    float dz = coordIn[i*3+2] - coordIn[col*3+2];
    float radial = dx*dx + dy*dy + dz*dz;
    float inv = frcp(__builtin_amdgcn_sqrtf(radial + 1e-8f) + 1.f);
    float ex = x0[i*3+0] - x0[col*3+0];
    float ey = x0[i*3+1] - x0[col*3+1];
    float ez = x0[i*3+2] - x0[col*3+2];
    float e0 = ex*ex + ey*ey + ez*ez;
    float em = nmi * nm[col] * ((t == ir) ? 0.f : 1.f);

    __syncthreads();

    {
        float4 g4 = make_float4(dx*inv, dy*inv, dz*inv, em);
        *(float4*)&sGeo[wv][e][0] = g4;
    }

    // ---- v0 = silu(Hr[i] + Hc[col] + radial*wr + e0*we) -> B-frags ----
    half_t* mybuf = (half_t*)sV[wv];
    const float4* hcv = (const float4*)(Hc + col * 64);
#pragma unroll
    for (int s = 0; s < 8; ++s) {
        float4 ha = hcv[2*s], hb = hcv[2*s+1];
        float z[8], so[8];
        z[0]=ha.x; z[1]=ha.y; z[2]=ha.z; z[3]=ha.w;
        z[4]=hb.x; z[5]=hb.y; z[6]=hb.z; z[7]=hb.w;
#pragma unroll
        for (int u = 0; u < 8; ++u) {
            int k = 8*s + u;
            z[u] = sHr[k] + z[u] + radial * sWr[k] + e0 * sWe[k];
        }
        silu4(z, so); silu4(z + 4, so + 4);
        half8 pk;
#pragma unroll
        for (int u = 0; u < 8; ++u) pk[u] = (half_t)so[u];
        int f = q * 2 + (s >> 2);
        *(half8*)&mybuf[f * 512 + ((s & 3) * 16 + c) * 8] = pk;
    }

    // ---- GEMM1: D1[out][edge] = W2 x v0^T  (C initialized with bias b2) ----
    const half8* bv = (const half8*)mybuf;
    f32x4 acc[4][4];
#pragma unroll
    for (int mt = 0; mt < 4; ++mt) {
        int row0 = 16*mt + 4*q;
#pragma unroll
        for (int nt = 0; nt < 4; ++nt)
#pragma unroll
            for (int r = 0; r < 4; ++r) acc[mt][nt][r] = sB2[row0 + r];
    }
    {
        const half8* a2v = (const half8*)wf2;
        half8 a2[8];
#pragma unroll
        for (int g = 0; g < 8; ++g) a2[g] = a2v[g * 64 + e];
#pragma unroll
        for (int nt = 0; nt < 4; ++nt) {
            half8 b0 = bv[(nt*2+0)*64 + e];
            half8 b1 = bv[(nt*2+1)*64 + e];
#pragma unroll
            for (int mt = 0; mt < 4; ++mt) {
                acc[mt][nt] = __builtin_amdgcn_mfma_f32_16x16x32_f16(a2[mt*2+0], b0, acc[mt][nt], 0, 0, 0);
                acc[mt][nt] = __builtin_amdgcn_mfma_f32_16x16x32_f16(a2[mt*2+1], b1, acc[mt][nt], 0, 0, 0);
            }
        }
    }

    // ---- silu + attention dot (bias already in acc) ----
    float attp[4] = {0.f, 0.f, 0.f, 0.f};
#pragma unroll
    for (int mt = 0; mt < 4; ++mt) {
        int row0 = 16*mt + 4*q;
#pragma unroll
        for (int nt = 0; nt < 4; ++nt) {
            float z[4], so[4];
#pragma unroll
            for (int r = 0; r < 4; ++r) z[r] = acc[mt][nt][r];
            silu4(z, so);
#pragma unroll
            for (int r = 0; r < 4; ++r) {
                acc[mt][nt][r] = so[r];
                attp[nt] += so[r] * sAttw[row0 + r];
            }
        }
    }
#pragma unroll
    for (int nt = 0; nt < 4; ++nt) {
        float v = attp[nt];
        v += __shfl_xor(v, 16);
        v += __shfl_xor(v, 32);
        attp[nt] = v;
    }
    float scale[4];
    {
        float d0 = 1.f + fexpn(-(attp[0] + attb0));
        float d1 = 1.f + fexpn(-(attp[1] + attb0));
        float d2 = 1.f + fexpn(-(attp[2] + attb0));
        float d3 = 1.f + fexpn(-(attp[3] + attb0));
        float iv[4]; inv4(d0, d1, d2, d3, iv);
#pragma unroll
        for (int nt = 0; nt < 4; ++nt) scale[nt] = iv[nt] * sGeo[wv][16*nt + c][3];
    }

    // ---- gate + agg partials + write mg as GEMM2 B-frags (acc dies here) ----
    float aggp[4][4];
#pragma unroll
    for (int mt = 0; mt < 4; ++mt)
#pragma unroll
        for (int r = 0; r < 4; ++r) aggp[mt][r] = 0.f;
#pragma unroll
    for (int mt = 0; mt < 4; ++mt) {
        int kbase = 16*mt + 4*q;
        int fof = ((kbase >> 5) * 512) + (((kbase >> 3) & 3) * 128) + (kbase & 7);
#pragma unroll
        for (int nt = 0; nt < 4; ++nt) {
            half4 pk;
#pragma unroll
            for (int r = 0; r < 4; ++r) {
                float v = acc[mt][nt][r] * scale[nt];
                aggp[mt][r] += v;
                pk[r] = (half_t)v;
            }
            *(half4*)&mybuf[nt*1024 + fof + c*8] = pk;
        }
    }

    // a1 load AFTER acc is dead (register-peak discipline); latency hidden by reductions
    half8 a1[8];
    {
        const half8* a1v = (const half8*)wf1;
#pragma unroll
        for (int g = 0; g < 8; ++g) a1[g] = a1v[g * 64 + e];
    }

#pragma unroll
    for (int mt = 0; mt < 4; ++mt)
#pragma unroll
        for (int r = 0; r < 4; ++r) {
            float v = aggp[mt][r];
            v += __shfl_xor(v, 1); v += __shfl_xor(v, 2);
            v += __shfl_xor(v, 4); v += __shfl_xor(v, 8);
            if (c == 0) atomicAdd(&sAgg[16*mt + 4*q + r], v);
        }

    // ---- GEMM2: D2[out][edge] = Wc1 x mg^T  (C initialized with bias bc1) ----
    f32x4 acc2[4][4];
#pragma unroll
    for (int mt = 0; mt < 4; ++mt) {
        int row0 = 16*mt + 4*q;
#pragma unroll
        for (int nt = 0; nt < 4; ++nt)
#pragma unroll
            for (int r = 0; r < 4; ++r) acc2[mt][nt][r] = sBc1[row0 + r];
    }
#pragma unroll
    for (int nt = 0; nt < 4; ++nt) {
        half8 b0 = bv[(nt*2+0)*64 + e];
        half8 b1 = bv[(nt*2+1)*64 + e];
#pragma unroll
        for (int mt = 0; mt < 4; ++mt) {
            acc2[mt][nt] = __builtin_amdgcn_mfma_f32_16x16x32_f16(a1[mt*2+0], b0, acc2[mt][nt], 0, 0, 0);
            acc2[mt][nt] = __builtin_amdgcn_mfma_f32_16x16x32_f16(a1[mt*2+1], b1, acc2[mt][nt], 0, 0, 0);
        }
    }

    // ---- phi = tanh( silu(D2) . wc2 ), trans, coord reduction ----
    float php[4] = {0.f, 0.f, 0.f, 0.f};
#pragma unroll
    for (int mt = 0; mt < 4; ++mt) {
        int row0 = 16*mt + 4*q;
#pragma unroll
        for (int nt = 0; nt < 4; ++nt) {
            float z[4], so[4];
#pragma unroll
            for (int r = 0; r < 4; ++r) z[r] = acc2[mt][nt][r];
            silu4(z, so);
#pragma unroll
            for (int r = 0; r < 4; ++r) php[nt] += so[r] * sWc2[row0 + r];
        }
    }
#pragma unroll
    for (int nt = 0; nt < 4; ++nt) {
        float v = php[nt];
        v += __shfl_xor(v, 16);
        v += __shfl_xor(v, 32);
        php[nt] = v;
    }
    float tnh[4];
    {
        float d0 = fexpn(2.f * php[0]) + 1.f;
        float d1 = fexpn(2.f * php[1]) + 1.f;
        float d2 = fexpn(2.f * php[2]) + 1.f;
        float d3 = fexpn(2.f * php[3]) + 1.f;
        float iv[4]; inv4(d0, d1, d2, d3, iv);
#pragma unroll
        for (int nt = 0; nt < 4; ++nt) tnh[nt] = 1.f - 2.f * iv[nt];
    }
    float tx = 0.f, ty = 0.f, tz = 0.f;
#pragma unroll
    for (int nt = 0; nt < 4; ++nt) {
        float4 g4 = *(float4*)&sGeo[wv][16*nt + c][0];
        float tr = tnh[nt] * CRANGE * g4.w;
        tx += g4.x * tr; ty += g4.y * tr; tz += g4.z * tr;
    }
    tx += __shfl_xor(tx, 1); tx += __shfl_xor(tx, 2); tx += __shfl_xor(tx, 4); tx += __shfl_xor(tx, 8);
    ty += __shfl_xor(ty, 1); ty += __shfl_xor(ty, 2); ty += __shfl_xor(ty, 4); ty += __shfl_xor(ty, 8);
    tz += __shfl_xor(tz, 1); tz += __shfl_xor(tz, 2); tz += __shfl_xor(tz, 4); tz += __shfl_xor(tz, 8);
    if (e == 0) {
        atomicAdd(&sCoord[0], tx);
        atomicAdd(&sCoord[1], ty);
        atomicAdd(&sCoord[2], tz);
    }

    __syncthreads();   // sAgg / sCoord complete; sV free for reuse

    // ================= fused tail: node MLP + next-layer Hr/Hc =================
    float* sT   = (float*)&sV[0][0];
    float* sIn  = sT;           // 128
    float* sP   = sT + 128;     // 256
    float* sU   = sT + 384;     // 64
    float* sHn  = sT + 448;     // 64
    float* sPB  = sT + 512;     // 256

    if (t < 64) sIn[t] = hbuf[i * 64 + t];
    else if (t < 128) sIn[t] = sAgg[t - 64];
    if (t >= 128 && t < 131) {
        int d = t - 128;
        coordOut[i * 3 + d] = (coordIn[i * 3 + d] + sCoord[d]) * nmi;
    }
    __syncthreads();

    const int cc = t & 63, p = t >> 6;
    {
        float a = 0.f;
        const float* w = nw1T + (p * 32) * 64 + cc;
#pragma unroll
        for (int k = 0; k < 32; ++k) a += w[k * 64] * sIn[p * 32 + k];
        sP[p * 64 + cc] = a;
    }
    __syncthreads();
    if (t < 64) sU[t] = fsilu(sP[t] + sP[64 + t] + sP[128 + t] + sP[192 + t] + nb1[t]);
    __syncthreads();
    {
        float a = 0.f;
        const float* w = nw2T + (p * 16) * 64 + cc;
#pragma unroll
        for (int k = 0; k < 16; ++k) a += w[k * 64] * sU[p * 16 + k];
        sP[p * 64 + cc] = a;
    }
    __syncthreads();
    if (t < 64) {
        float hn = (sIn[t] + sP[t] + sP[64 + t] + sP[128 + t] + sP[192 + t] + nb2[t]) * nmi;
        hbuf[i * 64 + t] = hn;
        sHn[t] = hn;
    }
    __syncthreads();
    {
        float a = 0.f, b2 = 0.f;
        const float* wa = ew1aTn + (p * 16) * 64 + cc;
        const float* wb = ew1bTn + (p * 16) * 64 + cc;
#pragma unroll
        for (int k = 0; k < 16; ++k) {
            float hv = sHn[p * 16 + k];
            a  += wa[k * 64] * hv;
            b2 += wb[k * 64] * hv;
        }
        sP[p * 64 + cc] = a;
        sPB[p * 64 + cc] = b2;
    }
    __syncthreads();
    if (t < 64) {
        Hr[i * 64 + t]  = sP[t] + sP[64 + t] + sP[128 + t] + sP[192 + t] + eb1n[t];
        HcO[i * 64 + t] = sPB[t] + sPB[64 + t] + sPB[128 + t] + sPB[192 + t];
    }
}

// ---------------- K4: vel = coord - x0, remove masked mean per batch ----------------
__global__ void k_final(const float* __restrict__ coord, const float* __restrict__ x0,
                        const float* __restrict__ nm, float* __restrict__ out) {
    int b = blockIdx.x;
    int t = threadIdx.x;
    int i = b * 256 + t;
    int lane = t & 63;
    float m = nm[i];
    float vx = (coord[i * 3 + 0] - x0[i * 3 + 0]) * m;
    float vy = (coord[i * 3 + 1] - x0[i * 3 + 1]) * m;
    float vz = (coord[i * 3 + 2] - x0[i * 3 + 2]) * m;
    __shared__ float red[4];
    if (t < 4) red[t] = 0.f;
    __syncthreads();
    float sx = vx, sy = vy, sz = vz, sn = m;
#pragma unroll
    for (int off = 1; off < 64; off <<= 1) {
        sx += __shfl_xor(sx, off);
        sy += __shfl_xor(sy, off);
        sz += __shfl_xor(sz, off);
        sn += __shfl_xor(sn, off);
    }
    if (lane == 0) {
        atomicAdd(&red[0], sx); atomicAdd(&red[1], sy);
        atomicAdd(&red[2], sz); atomicAdd(&red[3], sn);
    }
    __syncthreads();
    float invNs = frcp(red[3]);
    out[b * 768 + t * 3 + 0] = vx - red[0] * invNs * m;
    out[b * 768 + t * 3 + 1] = vy - red[1] * invNs * m;
    out[b * 768 + t * 3 + 2] = vz - red[2] * invNs * m;
}

extern "C" void kernel_launch(void* const* d_in, const int* in_sizes, int n_in,
                              void* d_out, int out_size, void* d_ws, size_t ws_size,
                              hipStream_t stream) {
    const float* t_in    = (const float*)d_in[0];
    const float* x_in    = (const float*)d_in[1];
    const float* at_in   = (const float*)d_in[2];
    const float* aa_in   = (const float*)d_in[3];
    const float* ap_in   = (const float*)d_in[4];
    const float* nm_in   = (const float*)d_in[5];
    const float* emb_w   = (const float*)d_in[6];
    const float* emb_b   = (const float*)d_in[7];
    const float* edge_w1 = (const float*)d_in[8];
    const float* edge_b1 = (const float*)d_in[9];
    const float* edge_w2 = (const float*)d_in[10];
    const float* edge_b2 = (const float*)d_in[11];
    const float* node_w1 = (const float*)d_in[12];
    const float* node_b1 = (const float*)d_in[13];
    const float* node_w2 = (const float*)d_in[14];
    const float* node_b2 = (const float*)d_in[15];
    const float* coord_w1= (const float*)d_in[16];
    const float* coord_b1= (const float*)d_in[17];
    const float* att_w   = (const float*)d_in[18];
    const float* att_b   = (const float*)d_in[19];
    const float* coord_w2= (const float*)d_in[20];

    float* ws  = (float*)d_ws;
    float* h   = ws;                  // 131072
    float* Hr  = h + 131072;          // 131072
    float* HcA = Hr + 131072;         // 131072
    float* HcB = HcA + 131072;        // 131072
    float* x0  = HcB + 131072;        // 6144
    float* cA  = x0 + 6144;           // 6144
    float* cB  = cA + 6144;           // 6144
    float* base = cB + 6144;
    half_t* wf = (half_t*)base;       // 32768 halves = 16384 float slots
    float* trT = base + 16384;        // 81920 floats: per layer [nw1T 8192][nw2T 4096][ew1aT 4096][ew1bT 4096]

    float* out = (float*)d_out;

    k_prep<<<336, 256, 0, stream>>>(edge_w2, coord_w1, node_w1, node_w2, edge_w1, wf, trT);
    k_init<<<2048, 64, 0, stream>>>(t_in, x_in, at_in, aa_in, ap_in, nm_in, emb_w, emb_b,
                                    trT + 12288, trT + 16384, edge_b1,
                                    h, Hr, HcA, x0, cA);

    for (int l = 0; l < 4; ++l) {
        const float* ew1 = edge_w1 + l * 8320;
        const float* eb2 = edge_b2 + l * 64;
        const float* cb1 = coord_b1 + l * 64;
        const float* aw  = att_w + l * 64;
        const float* ab  = att_b + l;
        const float* cw2 = coord_w2 + l * 64;
        const float* nb1 = node_b1 + l * 64;
        const float* nb2 = node_b2 + l * 64;

        const float* trL = trT + l * 20480;
        int ln = (l + 1) & 3;
        const float* trN = trT + ln * 20480;

        const float* cin  = (l & 1) ? cB : cA;
        float*       cout = (l & 1) ? cA : cB;
        const float* HcR  = (l & 1) ? HcB : HcA;
        float*       HcW  = (l & 1) ? HcA : HcB;

        k_edge<<<2048, 256, 0, stream>>>(cin, x0, Hr, HcR, ew1, eb2, cb1,
                                         aw, ab, cw2, nm_in,
                                         wf + l * 8192, wf + l * 8192 + 4096,
                                         h, trL, trL + 8192, nb1, nb2,
                                         trN + 12288, trN + 16384, edge_b1 + ln * 64,
                                         HcW, cout);
    }

    k_final<<<8, 256, 0, stream>>>(cA, x0, nm_in, out);
}